// Round 9
// baseline (193.387 us; speedup 1.0000x reference)
//
#include <hip/hip_runtime.h>
#include <hip/hip_bf16.h>

#define U_ 2048
#define T_ 512
#define K_ 128
#define B_ 32
#define RHO_ 0.99f
#define CPB 128      // chains per block
#define NTILES 9     // 16-col tiles covering 128+15 cols
#define NSLOTS 10    // W ring slots (1 spare staged ahead)

typedef __attribute__((ext_vector_type(8))) short short8;
typedef __attribute__((ext_vector_type(4))) float f32x4;

__device__ __forceinline__ unsigned short bf16_rne(float x) {
  unsigned int u = __float_as_uint(x);
  u += 0x7FFFu + ((u >> 16) & 1u);
  return (unsigned short)(u >> 16);
}

#define GLOAD_LDS16(gsrc, ldst)                                        \
  __builtin_amdgcn_global_load_lds(                                    \
      (const __attribute__((address_space(1))) void*)(gsrc),           \
      (__attribute__((address_space(3))) void*)(ldst), 16, 0, 0)

// ---------------- converts ----------------
// A [16384][128] fp32 -> Ab [16384][256] bf16 (k<128: hi, k>=128: lo residual)
__global__ __launch_bounds__(256) void convert_a_kernel(
    const float* __restrict__ A, unsigned short* __restrict__ Ab) {
  const int gi = blockIdx.x * 256 + threadIdx.x;
  const int m = gi >> 5;          // needs 2048 blocks
  const int kq = (gi & 31) << 2;
  const float4 v = *(const float4*)&A[(size_t)m * K_ + kq];
  ushort4 hi, lo;
  hi.x = bf16_rne(v.x); hi.y = bf16_rne(v.y); hi.z = bf16_rne(v.z); hi.w = bf16_rne(v.w);
  lo.x = bf16_rne(v.x - __uint_as_float((unsigned)hi.x << 16));
  lo.y = bf16_rne(v.y - __uint_as_float((unsigned)hi.y << 16));
  lo.z = bf16_rne(v.z - __uint_as_float((unsigned)hi.z << 16));
  lo.w = bf16_rne(v.w - __uint_as_float((unsigned)hi.w << 16));
  *(ushort4*)&Ab[(size_t)m * 256 + kq] = hi;
  *(ushort4*)&Ab[(size_t)m * 256 + 128 + kq] = lo;
}

// W [128][2048] fp32 -> Wbt [2048][256] bf16 transposed, duplicated along k.
__global__ __launch_bounds__(256) void convert_w_kernel(
    const float* __restrict__ W, unsigned short* __restrict__ Wbt) {
  const int gi = blockIdx.x * 256 + threadIdx.x;   // 65536 threads
  const int kq = gi >> 11;        // 0..31
  const int n = gi & 2047;
  const int k = kq << 2;
  ushort4 w;
  w.x = bf16_rne(W[(size_t)(k + 0) * U_ + n]);
  w.y = bf16_rne(W[(size_t)(k + 1) * U_ + n]);
  w.z = bf16_rne(W[(size_t)(k + 2) * U_ + n]);
  w.w = bf16_rne(W[(size_t)(k + 3) * U_ + n]);
  *(ushort4*)&Wbt[(size_t)n * 256 + k] = w;
  *(ushort4*)&Wbt[(size_t)n * 256 + 128 + k] = w;
}

// -------- v11: v10 + counted-vmcnt barrier + deferred stores + short chain ---
// v10 structure (proven 192.7us total) with the store-drain removed from the
// per-iter critical path:
//  * scan results kept in hreg[16]; stores DEFERRED to next iter, issued
//    right after the stage loads.  Barrier becomes
//    "s_waitcnt vmcnt(16) lgkmcnt(0); s_barrier": only the 6 stage loads
//    (strictly older, sched_barrier-fenced) drain; the 16 NT stores stay in
//    flight across the barrier (T4; legal: out regions disjoint, never read).
//  * ALL staging done by the scan waves (0-1) so the counted waitcnt is
//    wave-uniform: waves 2-3 issue no vmem at all (nothing to drain); wave 2
//    takes the 9th MFMA col-tile as compensation.
//  * shorter recurrence chain: x' = (u'+0.99) - 1.98*rcp(exp2(c*x)+1)
//    (5 dependent ops; h = 1-2*rcp computed OFF the chain for the store).
__global__ __launch_bounds__(256, 2) void fused_gemm_scan5_kernel(
    const unsigned short* __restrict__ Ab, const unsigned short* __restrict__ Wbt,
    const float* __restrict__ bias, const float* __restrict__ h0,
    float* __restrict__ out) {
  __shared__ unsigned short Wl[NSLOTS * 2048];   // 40 KB: 10 slots x 16n x 128k
  __shared__ unsigned short Al[2][4096];         // 16 KB: 2 x 16t x 256k
  __shared__ float u_lds[2][16 * 146];           // 18.25 KB
  const int tid = threadIdx.x;
  // XCD-aware remap: xcd = id&7 owns 4 whole batches -> Ab panel L2-resident.
  const int id = blockIdx.x + (blockIdx.y << 4);   // 0..511
  const int xcd = id & 7;
  const int wk = id >> 3;                          // 0..63
  const int b = (xcd << 2) + (wk >> 4);            // batch 0..31
  const int bx = wk & 15;                          // chain group 0..15
  const int c0 = bx << 7;
  const int cbase = bx << 3;                       // col-tile base (16-col units)
  const int wave = tid >> 6;
  const int lane = tid & 63;
  const int r = lane & 15;
  const int q = lane >> 4;

  const unsigned short* const aBase = Ab + (((size_t)b * T_) << 8);

  // ---- prologue: waves 0-1 stage A tile 0 + W slots 0..8 ----
  if (tid < 128) {
    #pragma unroll
    for (int k = 0; k < 4; ++k) {
      const int p = tid + (k << 7);            // A granule 0..511
      const int row = p >> 5, pg = p & 31;
      GLOAD_LDS16(aBase + ((size_t)row << 8) + ((pg ^ (row & 7)) << 3),
                  &Al[0][p << 3]);
    }
    #pragma unroll
    for (int j = 0; j < NTILES; ++j) {
      const int g = (cbase + j) & 127;
      #pragma unroll
      for (int k = 0; k < 2; ++k) {
        const int p = tid + (k << 7);          // W granule 0..255
        const int row = p >> 4, pg = p & 15;
        GLOAD_LDS16(Wbt + ((size_t)((g << 4) + row) << 8) + ((pg ^ (row & 7)) << 3),
                    &Wl[(j << 11) + (p << 3)]);
      }
    }
  }
  float bv[3], nbv[3];
  bv[0] = bias[(c0 + (wave << 4) + r) & (U_ - 1)];
  bv[1] = bias[(c0 + ((wave + 4) << 4) + r) & (U_ - 1)];
  bv[2] = (wave == 2) ? bias[(c0 + 128 + r) & (U_ - 1)] : 0.0f;
  float h_prev = 0.0f;
  if (tid < CPB)
    h_prev = h0[((size_t)b << 11) + ((c0 + tid + U_ - 1) & (U_ - 1))];
  float hreg[16];

  __syncthreads();                     // prologue drain (full, once)

  for (int it = 0; it < T_ / 16; ++it) {
    const int cur = it & 1;
    const int t0 = it << 4;

    // ---- step 1a: scan waves issue next-iter stages (6 loads each) ----
    if (tid < 128 && it + 1 < T_ / 16) {
      #pragma unroll
      for (int k = 0; k < 4; ++k) {
        const int p = tid + (k << 7);
        const int row = p >> 5, pg = p & 31;
        GLOAD_LDS16(aBase + ((size_t)(t0 + 16 + row) << 8) + ((pg ^ (row & 7)) << 3),
                    &Al[cur ^ 1][p << 3]);
      }
      const int g = (cbase + it + NTILES) & 127;
      const int snew = (it + NTILES) % NSLOTS;
      #pragma unroll
      for (int k = 0; k < 2; ++k) {
        const int p = tid + (k << 7);
        const int row = p >> 4, pg = p & 15;
        GLOAD_LDS16(Wbt + ((size_t)((g << 4) + row) << 8) + ((pg ^ (row & 7)) << 3),
                    &Wl[(snew << 11) + (p << 3)]);
      }
    }
    if (it + 1 < T_ / 16) {
      nbv[0] = bias[(c0 + t0 + 16 + (wave << 4) + r) & (U_ - 1)];
      nbv[1] = bias[(c0 + t0 + 16 + ((wave + 4) << 4) + r) & (U_ - 1)];
      if (wave == 2) nbv[2] = bias[(c0 + t0 + 16 + 128 + r) & (U_ - 1)];
    }
    // fence: stage loads strictly OLDER than the deferred stores below,
    // so vmcnt(16) at the barrier drains exactly the loads.
    __builtin_amdgcn_sched_barrier(0);

    // ---- step 1b: deferred stores of prev iter's h values ----
    if (tid < CPB && it > 0) {
      const int t0p = t0 - 16;
      float* const orow = out + (((size_t)(b * T_ + t0p)) << 11);
      #pragma unroll
      for (int tt = 0; tt < 16; ++tt)
        __builtin_nontemporal_store(
            hreg[tt], &orow[((size_t)tt << 11) + ((c0 + tid + t0p + tt) & (U_ - 1))]);
    }

    // ---- step 2: fragments from LDS + MFMA (wave2 owns the 9th tile) ----
    short8 af[8];
    #pragma unroll
    for (int ks = 0; ks < 8; ++ks)
      af[ks] = *(const short8*)&Al[cur][(r << 8) + ((((ks << 2) + q) ^ (r & 7)) << 3)];

    #pragma unroll
    for (int u = 0; u < 3; ++u) {
      const int j = (u < 2) ? (wave + (u << 2)) : 8;
      if (u < 2 || wave == 2) {
        const int slot = (it + j) % NSLOTS;
        short8 bfk[4];
        #pragma unroll
        for (int ks = 0; ks < 4; ++ks)
          bfk[ks] = *(const short8*)&Wl[(slot << 11) + (r << 7) +
                                        ((((ks << 2) + q) ^ (r & 7)) << 3)];
        f32x4 acc = (f32x4){0.f, 0.f, 0.f, 0.f};
        #pragma unroll
        for (int ks = 0; ks < 8; ++ks)   // lo-half reuses same W (dup'd k)
          acc = __builtin_amdgcn_mfma_f32_16x16x32_bf16(af[ks], bfk[ks & 3], acc, 0, 0, 0);
        // ---- step 3: u + bias -> u_lds[cur] ----
        #pragma unroll
        for (int reg = 0; reg < 4; ++reg)
          u_lds[cur][((q << 2) + reg) * 146 + (j << 4) + r] = acc[reg] + bv[u];
      }
    }

    // ---- counted barrier: drain stage loads (oldest), keep stores in flight
    asm volatile("s_waitcnt vmcnt(16) lgkmcnt(0)\n\ts_barrier" ::: "memory");
    __builtin_amdgcn_sched_barrier(0);

    // ---- step 4: scan 16 steps; h kept in regs, stores deferred ----
    if (tid < CPB) {
      float uv[16];
      #pragma unroll
      for (int tt = 0; tt < 16; ++tt)
        uv[tt] = u_lds[cur][tt * 146 + tid + tt];
      // chain: x_{t+1} = (u_{t+1}+rho) - 2*rho*rcp_t;  h_t = 1 - 2*rcp_t
      float x = fmaf(RHO_, h_prev, uv[0]);
      #pragma unroll
      for (int tt = 0; tt < 16; ++tt) {
        float e = __builtin_amdgcn_exp2f(2.8853900817779268f * x);
        float rc = __builtin_amdgcn_rcpf(e + 1.0f);
        hreg[tt] = fmaf(-2.0f, rc, 1.0f);                  // off the chain
        if (tt < 15) x = fmaf(-2.0f * RHO_, rc, uv[tt + 1] + RHO_);
      }
      h_prev = hreg[15];
    }
    bv[0] = nbv[0]; bv[1] = nbv[1]; bv[2] = nbv[2];
  }

  // ---- epilogue: store the last tile's h values ----
  if (tid < CPB) {
    const int t0p = T_ - 16;
    float* const orow = out + (((size_t)(b * T_ + t0p)) << 11);
    #pragma unroll
    for (int tt = 0; tt < 16; ++tt)
      __builtin_nontemporal_store(
          hreg[tt], &orow[((size_t)tt << 11) + ((c0 + tid + t0p + tt) & (U_ - 1))]);
  }
}

// ---------------- fallback path (R1, proven correct) ----------------
__device__ __forceinline__ float fast_tanh(float x) {
  float e = __builtin_amdgcn_exp2f(2.8853900817779268f * x);
  return 1.0f - 2.0f * __builtin_amdgcn_rcpf(e + 1.0f);
}

__global__ __launch_bounds__(256) void ring_scan_kernel(
    float* __restrict__ buf, const float* __restrict__ h0) {
  const int b = blockIdx.y;
  const int c = (blockIdx.x << 8) + threadIdx.x;
  float* const base = buf + (size_t)b * (T_ * U_);
  float h = h0[((size_t)b << 11) + ((c + U_ - 1) & (U_ - 1))];
  float wA[8], wB[8];
  #pragma unroll
  for (int j = 0; j < 8; ++j)
    wA[j] = base[((size_t)j << 11) + ((c + j) & (U_ - 1))];
  for (int t0 = 0; t0 < T_; t0 += 16) {
    #pragma unroll
    for (int j = 0; j < 8; ++j) {
      const int t = t0 + 8 + j;
      wB[j] = base[((size_t)t << 11) + ((c + t) & (U_ - 1))];
    }
    #pragma unroll
    for (int j = 0; j < 8; ++j) {
      const int t = t0 + j;
      h = fast_tanh(fmaf(RHO_, h, wA[j]));
      base[((size_t)t << 11) + ((c + t) & (U_ - 1))] = h;
    }
    if (t0 + 16 < T_) {
      #pragma unroll
      for (int j = 0; j < 8; ++j) {
        const int t = t0 + 16 + j;
        wA[j] = base[((size_t)t << 11) + ((c + t) & (U_ - 1))];
      }
    }
    #pragma unroll
    for (int j = 0; j < 8; ++j) {
      const int t = t0 + 8 + j;
      h = fast_tanh(fmaf(RHO_, h, wB[j]));
      base[((size_t)t << 11) + ((c + t) & (U_ - 1))] = h;
    }
  }
}

__global__ __launch_bounds__(256, 4) void gemm_bias_kernel(
    const float* __restrict__ A, const float* __restrict__ W,
    const float* __restrict__ bias, float* __restrict__ out) {
  __shared__ float Asf[64][68];
  __shared__ float Bsf[64][64];
  const int tid = threadIdx.x;
  const int m0 = blockIdx.y << 6;
  const int n0 = blockIdx.x << 6;
  const int tx = tid & 15;
  const int ty = tid >> 4;
  float acc[4][4] = {};
  #pragma unroll
  for (int kb = 0; kb < 2; ++kb) {
    if (kb) __syncthreads();
    {
      const int c4 = tid & 15;
      const int r0 = tid >> 4;
      #pragma unroll
      for (int rr = 0; rr < 4; ++rr) {
        const int r = r0 + (rr << 4);
        const float4 v = *(const float4*)(A + (size_t)(m0 + r) * K_ + (kb << 6) + (c4 << 2));
        Asf[(c4 << 2) + 0][r] = v.x;
        Asf[(c4 << 2) + 1][r] = v.y;
        Asf[(c4 << 2) + 2][r] = v.z;
        Asf[(c4 << 2) + 3][r] = v.w;
      }
    }
    {
      const int c4 = tid & 15;
      const int r0 = tid >> 4;
      #pragma unroll
      for (int rr = 0; rr < 4; ++rr) {
        const int k = r0 + (rr << 4);
        *(float4*)&Bsf[k][c4 << 2] =
            *(const float4*)(W + (size_t)((kb << 6) + k) * U_ + n0 + (c4 << 2));
      }
    }
    __syncthreads();
    #pragma unroll 16
    for (int k = 0; k < 64; ++k) {
      const float4 a = *(const float4*)&Asf[k][ty << 2];
      const float4 b = *(const float4*)&Bsf[k][tx << 2];
      acc[0][0] = fmaf(a.x, b.x, acc[0][0]); acc[0][1] = fmaf(a.x, b.y, acc[0][1]);
      acc[0][2] = fmaf(a.x, b.z, acc[0][2]); acc[0][3] = fmaf(a.x, b.w, acc[0][3]);
      acc[1][0] = fmaf(a.y, b.x, acc[1][0]); acc[1][1] = fmaf(a.y, b.y, acc[1][1]);
      acc[1][2] = fmaf(a.y, b.z, acc[1][2]); acc[1][3] = fmaf(a.y, b.w, acc[1][3]);
      acc[2][0] = fmaf(a.z, b.x, acc[2][0]); acc[2][1] = fmaf(a.z, b.y, acc[2][1]);
      acc[2][2] = fmaf(a.z, b.z, acc[2][2]); acc[2][3] = fmaf(a.z, b.w, acc[2][3]);
      acc[3][0] = fmaf(a.w, b.x, acc[3][0]); acc[3][1] = fmaf(a.w, b.y, acc[3][1]);
      acc[3][2] = fmaf(a.w, b.z, acc[3][2]); acc[3][3] = fmaf(a.w, b.w, acc[3][3]);
    }
  }
  const float4 bv = *(const float4*)(bias + n0 + (tx << 2));
  #pragma unroll
  for (int i = 0; i < 4; ++i) {
    float4 o;
    o.x = acc[i][0] + bv.x; o.y = acc[i][1] + bv.y;
    o.z = acc[i][2] + bv.z; o.w = acc[i][3] + bv.w;
    *(float4*)(out + (size_t)(m0 + (ty << 2) + i) * U_ + n0 + (tx << 2)) = o;
  }
}

extern "C" void kernel_launch(void* const* d_in, const int* in_sizes, int n_in,
                              void* d_out, int out_size, void* d_ws, size_t ws_size,
                              hipStream_t stream) {
  const float* A    = (const float*)d_in[0];   // inputs [B,T,D_IN]
  const float* h0   = (const float*)d_in[1];   // [B,U]
  const float* W    = (const float*)d_in[2];   // kernel [D_IN,U]
  const float* bias = (const float*)d_in[3];   // [U]
  float* out = (float*)d_out;                  // [B,T,U]

  const size_t AB_BYTES = (size_t)B_ * T_ * 256 * 2;         // 8,388,608
  const size_t WB_BYTES = (size_t)U_ * 256 * 2;              // 1,048,576
  const size_t NEEDED = AB_BYTES + WB_BYTES;

  if (ws_size >= NEEDED) {
    unsigned short* Ab  = (unsigned short*)d_ws;
    unsigned short* Wbt = (unsigned short*)((char*)d_ws + AB_BYTES);

    convert_a_kernel<<<2048, 256, 0, stream>>>(A, Ab);
    convert_w_kernel<<<256, 256, 0, stream>>>(W, Wbt);
    dim3 fg(U_ / CPB, B_);              // (16, 32) = 512 blocks
    fused_gemm_scan5_kernel<<<fg, 256, 0, stream>>>(Ab, Wbt, bias, h0, out);
  } else {
    dim3 gemm_grid(U_ / 64, (B_ * T_) / 64);
    gemm_bias_kernel<<<gemm_grid, 256, 0, stream>>>(A, W, bias, out);
    dim3 scan_grid(U_ / 256, B_);       // (8, 32)
    ring_scan_kernel<<<scan_grid, 256, 0, stream>>>(out, h0);
  }
}

// Round 11
// 182.322 us; speedup vs baseline: 1.0607x; 1.0607x over previous
//
#include <hip/hip_runtime.h>
#include <hip/hip_bf16.h>

#define U_ 2048
#define T_ 512
#define K_ 128
#define B_ 32
#define RHO_ 0.99f
#define CPB 128      // chains per block
#define NTILES 9     // 16-col tiles covering 128+15 cols
#define NSLOTS 10    // W ring slots (1 spare staged ahead)
#define NIT (T_ / 16)

typedef __attribute__((ext_vector_type(8))) short short8;
typedef __attribute__((ext_vector_type(4))) float f32x4;

__device__ __forceinline__ unsigned short bf16_rne(float x) {
  unsigned int u = __float_as_uint(x);
  u += 0x7FFFu + ((u >> 16) & 1u);
  return (unsigned short)(u >> 16);
}

#define GLOAD_LDS16(gsrc, ldst)                                        \
  __builtin_amdgcn_global_load_lds(                                    \
      (const __attribute__((address_space(1))) void*)(gsrc),           \
      (__attribute__((address_space(3))) void*)(ldst), 16, 0, 0)

// ---------------- converts ----------------
// A [16384][128] fp32 -> Ab [16384][256] bf16 (k<128: hi, k>=128: lo residual)
__global__ __launch_bounds__(256) void convert_a_kernel(
    const float* __restrict__ A, unsigned short* __restrict__ Ab) {
  const int gi = blockIdx.x * 256 + threadIdx.x;
  const int m = gi >> 5;          // needs 2048 blocks
  const int kq = (gi & 31) << 2;
  const float4 v = *(const float4*)&A[(size_t)m * K_ + kq];
  ushort4 hi, lo;
  hi.x = bf16_rne(v.x); hi.y = bf16_rne(v.y); hi.z = bf16_rne(v.z); hi.w = bf16_rne(v.w);
  lo.x = bf16_rne(v.x - __uint_as_float((unsigned)hi.x << 16));
  lo.y = bf16_rne(v.y - __uint_as_float((unsigned)hi.y << 16));
  lo.z = bf16_rne(v.z - __uint_as_float((unsigned)hi.z << 16));
  lo.w = bf16_rne(v.w - __uint_as_float((unsigned)hi.w << 16));
  *(ushort4*)&Ab[(size_t)m * 256 + kq] = hi;
  *(ushort4*)&Ab[(size_t)m * 256 + 128 + kq] = lo;
}

// W [128][2048] fp32 -> Wbt [2048][256] bf16 transposed, duplicated along k.
__global__ __launch_bounds__(256) void convert_w_kernel(
    const float* __restrict__ W, unsigned short* __restrict__ Wbt) {
  const int gi = blockIdx.x * 256 + threadIdx.x;   // 65536 threads
  const int kq = gi >> 11;        // 0..31
  const int n = gi & 2047;
  const int k = kq << 2;
  ushort4 w;
  w.x = bf16_rne(W[(size_t)(k + 0) * U_ + n]);
  w.y = bf16_rne(W[(size_t)(k + 1) * U_ + n]);
  w.z = bf16_rne(W[(size_t)(k + 2) * U_ + n]);
  w.w = bf16_rne(W[(size_t)(k + 3) * U_ + n]);
  *(ushort4*)&Wbt[(size_t)n * 256 + k] = w;
  *(ushort4*)&Wbt[(size_t)n * 256 + 128 + k] = w;
}

// ------ v12: wave-specialized fused GEMM+scan (producer/consumer, barriers) --
// v11 post-mortem: neutral -> store drain wasn't the wall; the convoy was:
// scan waves serially did stage+stores+MFMA+scan.  v12 splits roles:
//   waves 2-3 (producers): stage A/W via global_load_lds + bias loads +
//     ALL 9 MFMA tiles + u-writes; barrier with vmcnt(0) lgkmcnt(0)
//     (their stage loads drain under their own MFMA).
//   waves 0-1 (scan): deferred NT stores + uv reads + 16-step chain;
//     barrier with lgkmcnt(0) ONLY -> NT stores never waited on.
// One barrier/iter caps producer lead at 1 iteration.  Disjointness at
// lead 1: stage targets Al[cur] / slot (it+9)%10 vs read sets Al[cur^1] /
// slots {it..it+8}%10; u_lds[cur^1] written while scan reads u_lds[cur].
// Scan's chain now runs CONCURRENTLY with producers' next MFMA phase.
__global__ __launch_bounds__(256, 2) void fused_gemm_scan6_kernel(
    const unsigned short* __restrict__ Ab, const unsigned short* __restrict__ Wbt,
    const float* __restrict__ bias, const float* __restrict__ h0,
    float* __restrict__ out) {
  __shared__ unsigned short Wl[NSLOTS * 2048];   // 40 KB: 10 slots x 16n x 128k
  __shared__ unsigned short Al[2][4096];         // 16 KB: 2 x 16t x 256k
  __shared__ float u_lds[2][16 * 146];           // 18.25 KB
  const int tid = threadIdx.x;
  // XCD-aware remap: xcd = id&7 owns 4 whole batches -> Ab panel L2-resident.
  const int id = blockIdx.x + (blockIdx.y << 4);   // 0..511
  const int xcd = id & 7;
  const int wk = id >> 3;                          // 0..63
  const int b = (xcd << 2) + (wk >> 4);            // batch 0..31
  const int bx = wk & 15;                          // chain group 0..15
  const int c0 = bx << 7;
  const int cbase = bx << 3;                       // col-tile base (16-col units)
  const int wave = tid >> 6;
  const int lane = tid & 63;
  const int r = lane & 15;
  const int q = lane >> 4;
  const bool producer = (wave >= 2);
  const int ptid = tid & 127;                      // producer-local 0..127

  const unsigned short* const aBase = Ab + (((size_t)b * T_) << 8);

  // ---- prologue: producers stage A tile 0 + W slots 0..8 ----
  if (producer) {
    #pragma unroll
    for (int k = 0; k < 4; ++k) {
      const int p = ptid + (k << 7);             // A granule 0..511
      const int row = p >> 5, pg = p & 31;
      GLOAD_LDS16(aBase + ((size_t)row << 8) + ((pg ^ (row & 7)) << 3),
                  &Al[0][p << 3]);
    }
    #pragma unroll
    for (int j = 0; j < NTILES; ++j) {
      const int g = (cbase + j) & 127;
      #pragma unroll
      for (int k = 0; k < 2; ++k) {
        const int p = ptid + (k << 7);           // W granule 0..255
        const int row = p >> 4, pg = p & 15;
        GLOAD_LDS16(Wbt + ((size_t)((g << 4) + row) << 8) + ((pg ^ (row & 7)) << 3),
                    &Wl[(j << 11) + (p << 3)]);
      }
    }
  }
  float h_prev = 0.0f;
  float hreg[16];
  if (!producer)
    h_prev = h0[((size_t)b << 11) + ((c0 + tid + U_ - 1) & (U_ - 1))];

  __syncthreads();                     // prologue drain (full, once)

  const int isw2 = (wave == 2) ? 1 : 0;

  for (int it = 0; it < NIT; ++it) {
    const int cur = it & 1;
    const int t0 = it << 4;

    if (producer) {
      // ---- stage next-iter A + W ring slot (drain covered by MFMA) ----
      if (it + 1 < NIT) {
        #pragma unroll
        for (int k = 0; k < 4; ++k) {
          const int p = ptid + (k << 7);
          const int row = p >> 5, pg = p & 31;
          GLOAD_LDS16(aBase + ((size_t)(t0 + 16 + row) << 8) + ((pg ^ (row & 7)) << 3),
                      &Al[cur ^ 1][p << 3]);
        }
        const int g = (cbase + it + NTILES) & 127;
        const int snew = (it + NTILES) % NSLOTS;
        #pragma unroll
        for (int k = 0; k < 2; ++k) {
          const int p = ptid + (k << 7);
          const int row = p >> 4, pg = p & 15;
          GLOAD_LDS16(Wbt + ((size_t)((g << 4) + row) << 8) + ((pg ^ (row & 7)) << 3),
                      &Wl[(snew << 11) + (p << 3)]);
        }
      }
      // ---- bias for this wave's tiles (early issue; used after MFMA) ----
      // wave2: j in {0,1,2,3,8}; wave3: j in {4,5,6,7}
      float bvv[5];
      #pragma unroll
      for (int u = 0; u < 5; ++u) {
        if (u < 4 || isw2) {
          const int j = (u < 4) ? ((isw2 ? 0 : 4) + u) : 8;
          bvv[u] = bias[(((cbase + it + j) & 127) << 4) + r];
        }
      }
      // ---- A fragments ----
      short8 af[8];
      #pragma unroll
      for (int ks = 0; ks < 8; ++ks)
        af[ks] = *(const short8*)&Al[cur][(r << 8) + ((((ks << 2) + q) ^ (r & 7)) << 3)];
      // ---- MFMA all 9 tiles over 2 waves; u+bias -> u_lds[cur] ----
      #pragma unroll
      for (int u = 0; u < 5; ++u) {
        if (u < 4 || isw2) {
          const int j = (u < 4) ? ((isw2 ? 0 : 4) + u) : 8;
          const int slot = (it + j) % NSLOTS;
          short8 bfk[4];
          #pragma unroll
          for (int ks = 0; ks < 4; ++ks)
            bfk[ks] = *(const short8*)&Wl[(slot << 11) + (r << 7) +
                                          ((((ks << 2) + q) ^ (r & 7)) << 3)];
          f32x4 acc = (f32x4){0.f, 0.f, 0.f, 0.f};
          #pragma unroll
          for (int ks = 0; ks < 8; ++ks)   // lo-half reuses same W (dup'd k)
            acc = __builtin_amdgcn_mfma_f32_16x16x32_bf16(af[ks], bfk[ks & 3], acc, 0, 0, 0);
          #pragma unroll
          for (int reg = 0; reg < 4; ++reg)
            u_lds[cur][((q << 2) + reg) * 146 + (j << 4) + r] = acc[reg] + bvv[u];
        }
      }
      // producers drain their stage/bias loads + LDS, then barrier
      asm volatile("s_waitcnt vmcnt(0) lgkmcnt(0)\n\ts_barrier" ::: "memory");
      __builtin_amdgcn_sched_barrier(0);
    } else {
      // ---- deferred NT stores of prev iter's h (never waited on) ----
      if (it > 0) {
        const int t0p = t0 - 16;
        float* const orow = out + (((size_t)(b * T_ + t0p)) << 11);
        #pragma unroll
        for (int tt = 0; tt < 16; ++tt)
          __builtin_nontemporal_store(
              hreg[tt], &orow[((size_t)tt << 11) + ((c0 + tid + t0p + tt) & (U_ - 1))]);
      }
      // scan waves: only LDS must be coherent; NT stores stay in flight
      asm volatile("s_waitcnt lgkmcnt(0)\n\ts_barrier" ::: "memory");
      __builtin_amdgcn_sched_barrier(0);
      // ---- scan 16 steps on the diagonal ----
      float uv[16];
      #pragma unroll
      for (int tt = 0; tt < 16; ++tt)
        uv[tt] = u_lds[cur][tt * 146 + tid + tt];
      // chain: x_{t+1} = (u_{t+1}+rho) - 2*rho*rcp_t;  h_t = 1 - 2*rcp_t
      float x = fmaf(RHO_, h_prev, uv[0]);
      #pragma unroll
      for (int tt = 0; tt < 16; ++tt) {
        float e = __builtin_amdgcn_exp2f(2.8853900817779268f * x);
        float rc = __builtin_amdgcn_rcpf(e + 1.0f);
        hreg[tt] = fmaf(-2.0f, rc, 1.0f);                  // off the chain
        if (tt < 15) x = fmaf(-2.0f * RHO_, rc, uv[tt + 1] + RHO_);
      }
      h_prev = hreg[15];
    }
  }

  // ---- epilogue: store the last tile's h values ----
  if (!producer) {
    const int t0p = T_ - 16;
    float* const orow = out + (((size_t)(b * T_ + t0p)) << 11);
    #pragma unroll
    for (int tt = 0; tt < 16; ++tt)
      __builtin_nontemporal_store(
          hreg[tt], &orow[((size_t)tt << 11) + ((c0 + tid + t0p + tt) & (U_ - 1))]);
  }
}

// ---------------- fallback path (R1, proven correct) ----------------
__device__ __forceinline__ float fast_tanh(float x) {
  float e = __builtin_amdgcn_exp2f(2.8853900817779268f * x);
  return 1.0f - 2.0f * __builtin_amdgcn_rcpf(e + 1.0f);
}

__global__ __launch_bounds__(256) void ring_scan_kernel(
    float* __restrict__ buf, const float* __restrict__ h0) {
  const int b = blockIdx.y;
  const int c = (blockIdx.x << 8) + threadIdx.x;
  float* const base = buf + (size_t)b * (T_ * U_);
  float h = h0[((size_t)b << 11) + ((c + U_ - 1) & (U_ - 1))];
  float wA[8], wB[8];
  #pragma unroll
  for (int j = 0; j < 8; ++j)
    wA[j] = base[((size_t)j << 11) + ((c + j) & (U_ - 1))];
  for (int t0 = 0; t0 < T_; t0 += 16) {
    #pragma unroll
    for (int j = 0; j < 8; ++j) {
      const int t = t0 + 8 + j;
      wB[j] = base[((size_t)t << 11) + ((c + t) & (U_ - 1))];
    }
    #pragma unroll
    for (int j = 0; j < 8; ++j) {
      const int t = t0 + j;
      h = fast_tanh(fmaf(RHO_, h, wA[j]));
      base[((size_t)t << 11) + ((c + t) & (U_ - 1))] = h;
    }
    if (t0 + 16 < T_) {
      #pragma unroll
      for (int j = 0; j < 8; ++j) {
        const int t = t0 + 16 + j;
        wA[j] = base[((size_t)t << 11) + ((c + t) & (U_ - 1))];
      }
    }
    #pragma unroll
    for (int j = 0; j < 8; ++j) {
      const int t = t0 + 8 + j;
      h = fast_tanh(fmaf(RHO_, h, wB[j]));
      base[((size_t)t << 11) + ((c + t) & (U_ - 1))] = h;
    }
  }
}

__global__ __launch_bounds__(256, 4) void gemm_bias_kernel(
    const float* __restrict__ A, const float* __restrict__ W,
    const float* __restrict__ bias, float* __restrict__ out) {
  __shared__ float Asf[64][68];
  __shared__ float Bsf[64][64];
  const int tid = threadIdx.x;
  const int m0 = blockIdx.y << 6;
  const int n0 = blockIdx.x << 6;
  const int tx = tid & 15;
  const int ty = tid >> 4;
  float acc[4][4] = {};
  #pragma unroll
  for (int kb = 0; kb < 2; ++kb) {
    if (kb) __syncthreads();
    {
      const int c4 = tid & 15;
      const int r0 = tid >> 4;
      #pragma unroll
      for (int rr = 0; rr < 4; ++rr) {
        const int r = r0 + (rr << 4);
        const float4 v = *(const float4*)(A + (size_t)(m0 + r) * K_ + (kb << 6) + (c4 << 2));
        Asf[(c4 << 2) + 0][r] = v.x;
        Asf[(c4 << 2) + 1][r] = v.y;
        Asf[(c4 << 2) + 2][r] = v.z;
        Asf[(c4 << 2) + 3][r] = v.w;
      }
    }
    {
      const int c4 = tid & 15;
      const int r0 = tid >> 4;
      #pragma unroll
      for (int rr = 0; rr < 4; ++rr) {
        const int k = r0 + (rr << 4);
        *(float4*)&Bsf[k][c4 << 2] =
            *(const float4*)(W + (size_t)((kb << 6) + k) * U_ + n0 + (c4 << 2));
      }
    }
    __syncthreads();
    #pragma unroll 16
    for (int k = 0; k < 64; ++k) {
      const float4 a = *(const float4*)&Asf[k][ty << 2];
      const float4 b = *(const float4*)&Bsf[k][tx << 2];
      acc[0][0] = fmaf(a.x, b.x, acc[0][0]); acc[0][1] = fmaf(a.x, b.y, acc[0][1]);
      acc[0][2] = fmaf(a.x, b.z, acc[0][2]); acc[0][3] = fmaf(a.x, b.w, acc[0][3]);
      acc[1][0] = fmaf(a.y, b.x, acc[1][0]); acc[1][1] = fmaf(a.y, b.y, acc[1][1]);
      acc[1][2] = fmaf(a.y, b.z, acc[1][2]); acc[1][3] = fmaf(a.y, b.w, acc[1][3]);
      acc[2][0] = fmaf(a.z, b.x, acc[2][0]); acc[2][1] = fmaf(a.z, b.y, acc[2][1]);
      acc[2][2] = fmaf(a.z, b.z, acc[2][2]); acc[2][3] = fmaf(a.z, b.w, acc[2][3]);
      acc[3][0] = fmaf(a.w, b.x, acc[3][0]); acc[3][1] = fmaf(a.w, b.y, acc[3][1]);
      acc[3][2] = fmaf(a.w, b.z, acc[3][2]); acc[3][3] = fmaf(a.w, b.w, acc[3][3]);
    }
  }
  const float4 bv = *(const float4*)(bias + n0 + (tx << 2));
  #pragma unroll
  for (int i = 0; i < 4; ++i) {
    float4 o;
    o.x = acc[i][0] + bv.x; o.y = acc[i][1] + bv.y;
    o.z = acc[i][2] + bv.z; o.w = acc[i][3] + bv.w;
    *(float4*)(out + (size_t)(m0 + (ty << 2) + i) * U_ + n0 + (tx << 2)) = o;
  }
}

extern "C" void kernel_launch(void* const* d_in, const int* in_sizes, int n_in,
                              void* d_out, int out_size, void* d_ws, size_t ws_size,
                              hipStream_t stream) {
  const float* A    = (const float*)d_in[0];   // inputs [B,T,D_IN]
  const float* h0   = (const float*)d_in[1];   // [B,U]
  const float* W    = (const float*)d_in[2];   // kernel [D_IN,U]
  const float* bias = (const float*)d_in[3];   // [U]
  float* out = (float*)d_out;                  // [B,T,U]

  const size_t AB_BYTES = (size_t)B_ * T_ * 256 * 2;         // 8,388,608
  const size_t WB_BYTES = (size_t)U_ * 256 * 2;              // 1,048,576
  const size_t NEEDED = AB_BYTES + WB_BYTES;

  if (ws_size >= NEEDED) {
    unsigned short* Ab  = (unsigned short*)d_ws;
    unsigned short* Wbt = (unsigned short*)((char*)d_ws + AB_BYTES);

    convert_a_kernel<<<2048, 256, 0, stream>>>(A, Ab);
    convert_w_kernel<<<256, 256, 0, stream>>>(W, Wbt);
    dim3 fg(U_ / CPB, B_);              // (16, 32) = 512 blocks
    fused_gemm_scan6_kernel<<<fg, 256, 0, stream>>>(Ab, Wbt, bias, h0, out);
  } else {
    dim3 gemm_grid(U_ / 64, (B_ * T_) / 64);
    gemm_bias_kernel<<<gemm_grid, 256, 0, stream>>>(A, W, bias, out);
    dim3 scan_grid(U_ / 256, B_);       // (8, 32)
    ring_scan_kernel<<<scan_grid, 256, 0, stream>>>(out, h0);
  }
}